// Round 2
// baseline (360.025 us; speedup 1.0000x reference)
//
#include <hip/hip_runtime.h>
#include <hip/hip_bf16.h>
#include <stdint.h>
#include <math.h>

#define DEVI __device__ __forceinline__

typedef __attribute__((ext_vector_type(8))) __bf16    bf16x8;
typedef __attribute__((ext_vector_type(8))) _Float16  f16x8;
typedef __attribute__((ext_vector_type(4))) float     f32x4;

constexpr int BM = 128, BN = 128, BK = 64;

DEVI unsigned int pack2(float a, float b) {
  unsigned short ha = __builtin_bit_cast(unsigned short, __float2bfloat16(a));
  unsigned short hb = __builtin_bit_cast(unsigned short, __float2bfloat16(b));
  return (unsigned int)ha | ((unsigned int)hb << 16);
}

// ---------------------------------------------------------------------------
// Merged fp32 -> bf16 conversion for x, Wq, Wk, Wv in ONE launch.
// ---------------------------------------------------------------------------
__global__ __launch_bounds__(256) void k_cvt_all(const float* __restrict__ x,
                                                 const float* __restrict__ Wq,
                                                 const float* __restrict__ Wk,
                                                 const float* __restrict__ Wv,
                                                 __hip_bfloat16* __restrict__ xb,
                                                 __hip_bfloat16* __restrict__ Wqb,
                                                 __hip_bfloat16* __restrict__ Wkb,
                                                 __hip_bfloat16* __restrict__ Wvb) {
  int i = blockIdx.x * 256 + threadIdx.x;
  const float* src;
  __hip_bfloat16* dst;
  int k;
  if (i < 4194304) {
    src = x; dst = xb; k = i;
  } else {
    int j = i - 4194304;
    int w = j >> 18;
    k = j & 262143;
    src = (w == 0) ? Wq : (w == 1) ? Wk : Wv;
    dst = (w == 0) ? Wqb : (w == 1) ? Wkb : Wvb;
  }
  float4 f = ((const float4*)src)[k];
  uint2 u;
  u.x = pack2(f.x, f.y);
  u.y = pack2(f.z, f.w);
  ((uint2*)dst)[k] = u;
}

// ---------------------------------------------------------------------------
// Staging (256-thread blocks): global -> LDS via global_load_lds (16B/lane),
// wave-uniform LDS base. XOR swizzle on the GLOBAL column so ds_read_b128
// fragment reads spread across banks. LDS (row,k) at row*64 + ((k/8)^(row&7))*8 + k%8.
// ---------------------------------------------------------------------------
DEVI void stage_tile(const __hip_bfloat16* gbase, int ld, unsigned short* lds, int tid) {
#pragma unroll
  for (int j = 0; j < 4; ++j) {
    int g   = j * 256 + tid;
    int row = g >> 3;
    int cp  = g & 7;
    int c   = cp ^ (row & 7);
    const __hip_bfloat16* src = gbase + (size_t)row * ld + c * 8;
    unsigned short* dst = lds + (size_t)(j * 256 + (tid & ~63)) * 8;  // wave-uniform
    __builtin_amdgcn_global_load_lds((__attribute__((address_space(1))) void*)(src),
                                     (__attribute__((address_space(3))) void*)(dst),
                                     16, 0, 0);
  }
}

// Same staging for 512-thread blocks: one 128x64 half-tile (16KB) per call,
// 2 global_load_lds per wave.
DEVI void stage_half(const __hip_bfloat16* gbase, int ld, unsigned short* lds, int tid) {
#pragma unroll
  for (int j = 0; j < 2; ++j) {
    int g   = j * 512 + tid;
    int row = g >> 3;
    int cp  = g & 7;
    int c   = cp ^ (row & 7);
    const __hip_bfloat16* src = gbase + (size_t)row * ld + c * 8;
    unsigned short* dst = lds + (size_t)(j * 512 + (tid & ~63)) * 8;  // wave-uniform
    __builtin_amdgcn_global_load_lds((__attribute__((address_space(1))) void*)(src),
                                     (__attribute__((address_space(3))) void*)(dst),
                                     16, 0, 0);
  }
}

DEVI bf16x8 read_frag(const unsigned short* lds, int row, int kcol) {
  int c  = kcol >> 3;
  int cp = c ^ (row & 7);
  return *(const bf16x8*)(lds + row * 64 + cp * 8);
}

// ---------------------------------------------------------------------------
// 128x128x(64*ktiles) bf16 MFMA core, gemm_bt (unchanged; used by scores/pv).
// ---------------------------------------------------------------------------
DEVI void gemm_core(unsigned short* sA, unsigned short* sB,
                    const __hip_bfloat16* A0, int lda,
                    const __hip_bfloat16* B0, int ldb,
                    int ktiles, f32x4 (&acc)[4][4]) {
  const int tid  = threadIdx.x;
  const int lane = tid & 63;
  const int wid  = tid >> 6;
  const int quad = lane >> 4;
  const int lr   = lane & 15;
  const int wm   = (wid >> 1) * 64;
  const int wn   = (wid & 1) * 64;
  const f32x4 Z = {0.f, 0.f, 0.f, 0.f};
#pragma unroll
  for (int i = 0; i < 4; ++i)
#pragma unroll
    for (int j = 0; j < 4; ++j) acc[i][j] = Z;

  for (int kt = 0; kt < ktiles; ++kt) {
    stage_tile(A0 + kt * BK, lda, sA, tid);
    stage_tile(B0 + kt * BK, ldb, sB, tid);
    __syncthreads();
#pragma unroll
    for (int ks = 0; ks < BK; ks += 32) {
      bf16x8 af[4], bfr[4];
#pragma unroll
      for (int t = 0; t < 4; ++t) af[t]  = read_frag(sA, wm + t * 16 + lr, ks + quad * 8);
#pragma unroll
      for (int t = 0; t < 4; ++t) bfr[t] = read_frag(sB, wn + t * 16 + lr, ks + quad * 8);
#pragma unroll
      for (int i = 0; i < 4; ++i)
#pragma unroll
        for (int j = 0; j < 4; ++j)
          acc[i][j] = __builtin_amdgcn_mfma_f32_16x16x32_bf16(af[i], bfr[j], acc[i][j], 0, 0, 0);
    }
    __syncthreads();
  }
}

// ---------------------------------------------------------------------------
// Merged QKV projection, 256x256-tile 8-phase schedule (T3+T4+T5).
// 512 threads = 8 waves (2M x 4N), per-wave output 128x64. BK=64, NT=16.
// LDS 128 KiB: 2 buffers x {A0,A1,B0,B1} of 128x64 bf16 each.
// Phase plan per K-tile t (4 phases, 16 MFMA each):
//   ph1: ds_read A(mg0,ks0+ks1)+B(ks0) [12]; stage B0(t+1)->other buf; MFMA mg0*ks0
//   ph2: ds_read A(mg1,ks0+ks1)+B(ks1) [12]; stage B1(t+1)->other buf; MFMA mg1*ks0
//   ph3: stage A0(t+2)->this buf (all reads of this buf done at ph2);   MFMA mg0*ks1
//   ph4: stage A1(t+2)->this buf; s_waitcnt vmcnt(4);                   MFMA mg1*ks1
// vmcnt(4) = A(t+2) halves (4 per-wave loads) in flight; never 0 until tail.
// Barriers are __builtin_amdgcn_s_barrier() (m201 template primitive);
// only waitcnts are inline asm, each followed by sched_barrier(0) (rule #18).
// ---------------------------------------------------------------------------
DEVI void phase_in_lgkm() {
  __builtin_amdgcn_s_barrier();
  asm volatile("s_waitcnt lgkmcnt(0)" ::: "memory");
  __builtin_amdgcn_sched_barrier(0);
}
DEVI void phase_in() {
  __builtin_amdgcn_s_barrier();
  __builtin_amdgcn_sched_barrier(0);
}
DEVI void phase_out() {
  __builtin_amdgcn_sched_barrier(0);
  __builtin_amdgcn_s_barrier();
}

#define MFMA16(R0, AF, BF)                                                        \
  _Pragma("unroll") for (int i = 0; i < 4; ++i)                                   \
  _Pragma("unroll") for (int j = 0; j < 4; ++j)                                   \
    acc[(R0) + i][j] =                                                            \
        __builtin_amdgcn_mfma_f32_16x16x32_bf16(AF[i], BF[j], acc[(R0) + i][j], 0, 0, 0);

__global__ __launch_bounds__(512, 2) void k_proj_qkv2(const __hip_bfloat16* __restrict__ X,
                                                      const __hip_bfloat16* __restrict__ Wq,
                                                      const __hip_bfloat16* __restrict__ Wk,
                                                      const __hip_bfloat16* __restrict__ Wv,
                                                      const float* __restrict__ bq,
                                                      const float* __restrict__ bk,
                                                      const float* __restrict__ bv,
                                                      __hip_bfloat16* __restrict__ Q,
                                                      __hip_bfloat16* __restrict__ Kp,
                                                      __hip_bfloat16* __restrict__ Vt) {
  __shared__ unsigned short lds[65536];  // 128 KiB

  const int id = blockIdx.x;              // 768 = 8 XCD chunks of 96 (bijective)
  const int wg = (id & 7) * 96 + (id >> 3);
  const int mt = wg & 63;
  const int nt = (wg >> 6) & 3;
  const int w  = wg >> 8;                 // 0=Q 1=K 2=V
  const int m0 = mt * 256;
  const int n0 = nt * 256;

  const __hip_bfloat16* W    = (w == 0) ? Wq : (w == 1) ? Wk : Wv;
  const float*          bias = (w == 0) ? bq : (w == 1) ? bk : bv;
  const __hip_bfloat16* Ab = X + (size_t)m0 * 1024;
  const __hip_bfloat16* Bb = W + (size_t)n0 * 1024;

  const int tid  = threadIdx.x;
  const int lane = tid & 63;
  const int wid  = tid >> 6;
  const int quad = lane >> 4;
  const int lr   = lane & 15;
  const int widm = wid >> 2;   // 0..1 : which A half-tile
  const int widn = wid & 3;    // 0..3 : 64-col slice; B half = widn>>1, row base (widn&1)*64
  const int br0  = (widn & 1) * 64;

  f32x4 acc[8][4];
  const f32x4 Z = {0.f, 0.f, 0.f, 0.f};
#pragma unroll
  for (int i = 0; i < 8; ++i)
#pragma unroll
    for (int j = 0; j < 4; ++j) acc[i][j] = Z;

  // Prologue: tile0 fully (A0,A1,B0,B1 -> buf0), tile1 A-halves -> buf1.
  // Conservative m201-style prologue: full drain, then barrier.
  stage_half(Ab,               1024, lds + 0,            tid);
  stage_half(Ab + 131072,      1024, lds + 8192,         tid);
  stage_half(Bb,               1024, lds + 16384,        tid);
  stage_half(Bb + 131072,      1024, lds + 24576,        tid);
  stage_half(Ab + 64,          1024, lds + 32768,        tid);
  stage_half(Ab + 131072 + 64, 1024, lds + 32768 + 8192, tid);
  asm volatile("s_waitcnt vmcnt(0)" ::: "memory");
  __builtin_amdgcn_sched_barrier(0);
  __builtin_amdgcn_s_barrier();

  for (int t = 0; t < 16; ++t) {
    unsigned short* cur = lds + (t & 1) * 32768;
    unsigned short* nxt = lds + ((t + 1) & 1) * 32768;
    const unsigned short* Ar = cur + widm * 8192;
    const unsigned short* Br = cur + 16384 + (widn >> 1) * 8192;

    bf16x8 a0k0[4], a0k1[4], a1k0[4], a1k1[4], b0f[4], b1f[4];

    // ---- phase 1: reads mg0 (both ks) + B ks0; stage B0(t+1); MFMA mg0*ks0
#pragma unroll
    for (int i = 0; i < 4; ++i) {
      a0k0[i] = read_frag(Ar, i * 16 + lr, quad * 8);
      a0k1[i] = read_frag(Ar, i * 16 + lr, 32 + quad * 8);
    }
#pragma unroll
    for (int j = 0; j < 4; ++j) b0f[j] = read_frag(Br, br0 + j * 16 + lr, quad * 8);
    if (t < 15) stage_half(Bb + (t + 1) * 64, 1024, nxt + 16384, tid);
    phase_in_lgkm();
    __builtin_amdgcn_s_setprio(1);
    MFMA16(0, a0k0, b0f);
    __builtin_amdgcn_s_setprio(0);
    phase_out();

    // ---- phase 2: reads mg1 (both ks) + B ks1; stage B1(t+1); MFMA mg1*ks0
#pragma unroll
    for (int i = 0; i < 4; ++i) {
      a1k0[i] = read_frag(Ar, 64 + i * 16 + lr, quad * 8);
      a1k1[i] = read_frag(Ar, 64 + i * 16 + lr, 32 + quad * 8);
    }
#pragma unroll
    for (int j = 0; j < 4; ++j) b1f[j] = read_frag(Br, br0 + j * 16 + lr, 32 + quad * 8);
    if (t < 15) stage_half(Bb + 131072 + (t + 1) * 64, 1024, nxt + 24576, tid);
    phase_in_lgkm();
    __builtin_amdgcn_s_setprio(1);
    MFMA16(4, a1k0, b0f);
    __builtin_amdgcn_s_setprio(0);
    phase_out();

    // ---- phase 3: stage A0(t+2) into cur (all reads of this buf completed
    //      by phase 2's lgkmcnt(0) + barrier); MFMA mg0*ks1
    if (t < 14) stage_half(Ab + (t + 2) * 64, 1024, cur + 0, tid);
    phase_in();
    __builtin_amdgcn_s_setprio(1);
    MFMA16(0, a0k1, b1f);
    __builtin_amdgcn_s_setprio(0);
    phase_out();

    // ---- phase 4: stage A1(t+2); counted vmcnt (A(t+2) stays in flight);
    //      MFMA mg1*ks1
    if (t < 14) stage_half(Ab + 131072 + (t + 2) * 64, 1024, cur + 8192, tid);
    if (t < 14) asm volatile("s_waitcnt vmcnt(4)" ::: "memory");
    else        asm volatile("s_waitcnt vmcnt(0)" ::: "memory");
    __builtin_amdgcn_sched_barrier(0);
    phase_in();
    __builtin_amdgcn_s_setprio(1);
    MFMA16(4, a1k1, b1f);
    __builtin_amdgcn_s_setprio(0);
    phase_out();
  }

  // Epilogue
  float bvv[4];
#pragma unroll
  for (int j = 0; j < 4; ++j) bvv[j] = bias[n0 + widn * 64 + j * 16 + lr];

  if (w != 2) {
    __hip_bfloat16* C = (w == 0) ? Q : Kp;
#pragma unroll
    for (int i = 0; i < 8; ++i)
#pragma unroll
      for (int j = 0; j < 4; ++j) {
        int n = n0 + widn * 64 + j * 16 + lr;
#pragma unroll
        for (int r = 0; r < 4; ++r) {
          int m = m0 + widm * 128 + i * 16 + quad * 4 + r;
          C[(size_t)m * 1024 + n] = __float2bfloat16(acc[i][j][r] + bvv[j]);
        }
      }
  } else {
    const int b = m0 >> 11;
    __hip_bfloat16* Cb = Vt + ((size_t)b << 21);
    const int sb = (m0 & 2047) + widm * 128;
#pragma unroll
    for (int i = 0; i < 8; ++i)
#pragma unroll
      for (int j = 0; j < 4; ++j) {
        int n  = n0 + widn * 64 + j * 16 + lr;
        int s0 = sb + i * 16 + quad * 4;
        uint2 u;
        u.x = pack2(acc[i][j][0] + bvv[j], acc[i][j][1] + bvv[j]);
        u.y = pack2(acc[i][j][2] + bvv[j], acc[i][j][3] + bvv[j]);
        *(uint2*)(Cb + (size_t)n * 2048 + s0) = u;
      }
  }
}

// ---------------------------------------------------------------------------
// Scores: S[z,q,k] = (Q.K)/32, fp16, lower-triangular tiles only.
// Grid G*136; z = id & zmask (batch <-> XCD), triangular tile decode.
// ---------------------------------------------------------------------------
__global__ __launch_bounds__(256, 4) void k_scores(const __hip_bfloat16* __restrict__ Q,
                                                   const __hip_bfloat16* __restrict__ Kmat,
                                                   _Float16* __restrict__ S,
                                                   int b0, int zmask, int zshift) {
  __shared__ unsigned short sA[BM * BK];
  __shared__ unsigned short sB[BN * BK];
  const int id = blockIdx.x;
  const int z = id & zmask;
  const int b = b0 + z;
  const int i = id >> zshift;
  int qt = (int)((sqrtf(8.f * (float)i + 1.f) - 1.f) * 0.5f);
  while ((qt + 1) * (qt + 2) / 2 <= i) ++qt;
  while (qt * (qt + 1) / 2 > i) --qt;
  const int kt = i - qt * (qt + 1) / 2;

  const int m0 = qt * BM, n0 = kt * BN;
  f32x4 acc[4][4];
  const __hip_bfloat16* A0 = Q    + ((size_t)b << 21) + (size_t)m0 * 1024;
  const __hip_bfloat16* B0 = Kmat + ((size_t)b << 21) + (size_t)n0 * 1024;
  gemm_core(sA, sB, A0, 1024, B0, 1024, 16, acc);

  _Float16* Sb = S + ((size_t)z << 22);
  const int tid = threadIdx.x, lane = tid & 63, wid = tid >> 6;
  const int quad = lane >> 4, lr = lane & 15;
  const int wm = (wid >> 1) * 64, wn = (wid & 1) * 64;
#pragma unroll
  for (int i2 = 0; i2 < 4; ++i2)
#pragma unroll
    for (int j = 0; j < 4; ++j) {
      int n = n0 + wn + j * 16 + lr;
#pragma unroll
      for (int r = 0; r < 4; ++r) {
        int m = m0 + wm + i2 * 16 + quad * 4 + r;
        Sb[(size_t)m * 2048 + n] = (_Float16)(acc[i2][j][r] * 0.03125f);
      }
    }
}

// ---------------------------------------------------------------------------
// Row softmax over k<=q, in-place: 16B fp16x8 load (skipped entirely above
// the diagonal) and one 16B bf16x8 store per thread. k>q written as 0.
// ---------------------------------------------------------------------------
__global__ __launch_bounds__(256) void k_softmax(_Float16* __restrict__ S) {
  const int row = blockIdx.x;
  const int q = row & 2047;
  _Float16* srow = S + ((size_t)row << 11);
  const int t = threadIdx.x;
  const int k0 = t << 3;

  float v[8];
  float mx = -1e30f;
  if (k0 <= q) {
    f16x8 h = ((const f16x8*)srow)[t];
#pragma unroll
    for (int i = 0; i < 8; ++i) {
      float f = (float)h[i];
      v[i] = (k0 + i <= q) ? f : -1e30f;
      mx = fmaxf(mx, v[i]);
    }
  } else {
#pragma unroll
    for (int i = 0; i < 8; ++i) v[i] = -1e30f;
  }
#pragma unroll
  for (int off = 32; off > 0; off >>= 1) mx = fmaxf(mx, __shfl_xor(mx, off));
  __shared__ float rmax[4], rsum[4];
  if ((t & 63) == 0) rmax[t >> 6] = mx;
  __syncthreads();
  mx = fmaxf(fmaxf(rmax[0], rmax[1]), fmaxf(rmax[2], rmax[3]));

  float e[8], s = 0.f;
#pragma unroll
  for (int i = 0; i < 8; ++i) { e[i] = __expf(v[i] - mx); s += e[i]; }
#pragma unroll
  for (int off = 32; off > 0; off >>= 1) s += __shfl_xor(s, off);
  if ((t & 63) == 0) rsum[t >> 6] = s;
  __syncthreads();
  s = rsum[0] + rsum[1] + rsum[2] + rsum[3];
  const float inv = 1.0f / s;

  bf16x8 o;
#pragma unroll
  for (int i = 0; i < 8; ++i) o[i] = (__bf16)(e[i] * inv);
  ((bf16x8*)srow)[t] = o;
}

// ---------------------------------------------------------------------------
// PV: out[b,q,e] = sum_s P[q,s]*Vt[e,s], fp32 out. Load-balanced pairing:
// each block computes (qt=15-p, nt) then (qt=p, nt) -> uniform 36 ktiles.
// Grid G*64; z = id & zmask (batch<->XCD).
// ---------------------------------------------------------------------------
DEVI void pv_one(unsigned short* sA, unsigned short* sB,
                 const __hip_bfloat16* P, const __hip_bfloat16* VtB,
                 float* Cb, int qt, int nt) {
  const int m0 = qt * BM, n0 = nt * BN;
  const int ktiles = 2 * qt + 2;   // covers s in [0, (qt+1)*128)
  f32x4 acc[4][4];
  gemm_core(sA, sB, P + (size_t)m0 * 2048, 2048, VtB + (size_t)n0 * 2048, 2048, ktiles, acc);

  const int tid = threadIdx.x, lane = tid & 63, wid = tid >> 6;
  const int quad = lane >> 4, lr = lane & 15;
  const int wm = (wid >> 1) * 64, wn = (wid & 1) * 64;
#pragma unroll
  for (int i = 0; i < 4; ++i)
#pragma unroll
    for (int j = 0; j < 4; ++j) {
      int n = n0 + wn + j * 16 + lr;
#pragma unroll
      for (int r = 0; r < 4; ++r) {
        int m = m0 + wm + i * 16 + quad * 4 + r;
        Cb[(size_t)m * 1024 + n] = acc[i][j][r];
      }
    }
}

__global__ __launch_bounds__(256, 4) void k_pv(const _Float16* __restrict__ Sbase,
                                               const __hip_bfloat16* __restrict__ Vt,
                                               float* __restrict__ out,
                                               int b0, int zmask, int zshift) {
  __shared__ unsigned short sA[BM * BK];
  __shared__ unsigned short sB[BN * BK];
  const int id = blockIdx.x;
  const int z = id & zmask;
  const int b = b0 + z;
  const int r2 = id >> zshift;     // 0..63
  const int nt = r2 & 7;
  const int p  = (r2 >> 3) & 7;
  const __hip_bfloat16* P   = (const __hip_bfloat16*)(Sbase + ((size_t)z << 22));
  const __hip_bfloat16* VtB = Vt + ((size_t)b << 21);
  float* Cb = out + ((size_t)b << 21);
  pv_one(sA, sB, P, VtB, Cb, 15 - p, nt);   // long tile first
  pv_one(sA, sB, P, VtB, Cb, p, nt);        // short tile second
}

extern "C" void kernel_launch(void* const* d_in, const int* in_sizes, int n_in,
                              void* d_out, int out_size, void* d_ws, size_t ws_size,
                              hipStream_t stream) {
  const float* x  = (const float*)d_in[0];
  const float* Wq = (const float*)d_in[1];
  const float* bq = (const float*)d_in[2];
  const float* Wk = (const float*)d_in[3];
  const float* bk = (const float*)d_in[4];
  const float* Wv = (const float*)d_in[5];
  const float* bv = (const float*)d_in[6];
  float* out = (float*)d_out;

  char* ws = (char*)d_ws;
  const size_t MB32 = (size_t)33554432;
  const size_t MB64 = (size_t)67108864;

  __hip_bfloat16 *xb, *Wqb, *Wkb, *Wvb, *Q, *Kp, *Vt;
  _Float16* S;
  int G;
  if (ws_size >= (size_t)174063616) {
    // Big layout (166 MiB): [S 64MB (xb overlays first 32MB)] [W 6MB] [Q][K][Vt]
    S   = (_Float16*)(ws);
    xb  = (__hip_bfloat16*)(ws);                   // dead before S is written
    Wqb = (__hip_bfloat16*)(ws + MB64);
    Wkb = (__hip_bfloat16*)(ws + MB64 + 2097152);
    Wvb = (__hip_bfloat16*)(ws + MB64 + 4194304);
    Q   = (__hip_bfloat16*)(ws + MB64 + 6291456);
    Kp  = (__hip_bfloat16*)(ws + MB64 + 6291456 + MB32);
    Vt  = (__hip_bfloat16*)(ws + MB64 + 6291456 + 2 * MB32);
    G = 8;
  } else {
    // Small layout (134 MiB, proven): [xb 32MB == S 32MB] [W 6MB] [Q][K][Vt]
    S   = (_Float16*)(ws);
    xb  = (__hip_bfloat16*)(ws);
    Wqb = (__hip_bfloat16*)(ws + MB32);
    Wkb = (__hip_bfloat16*)(ws + MB32 + 2097152);
    Wvb = (__hip_bfloat16*)(ws + MB32 + 4194304);
    Q   = (__hip_bfloat16*)(ws + MB32 + 6291456);
    Kp  = (__hip_bfloat16*)(ws + 2 * MB32 + 6291456);
    Vt  = (__hip_bfloat16*)(ws + 3 * MB32 + 6291456);
    G = 4;
  }
  const int zmask  = G - 1;
  const int zshift = (G == 8) ? 3 : 2;

  dim3 blk(256);
  k_cvt_all<<<dim3(19456), blk, 0, stream>>>(x, Wq, Wk, Wv, xb, Wqb, Wkb, Wvb);
  k_proj_qkv2<<<dim3(768), dim3(512), 0, stream>>>(xb, Wqb, Wkb, Wvb, bq, bk, bv, Q, Kp, Vt);

  for (int b0 = 0; b0 < 8; b0 += G) {
    k_scores <<<dim3(G * 136),  blk, 0, stream>>>(Q, Kp, S, b0, zmask, zshift);
    k_softmax<<<dim3(G * 2048), blk, 0, stream>>>(S);
    k_pv     <<<dim3(G * 64),   blk, 0, stream>>>(S, Vt, out, b0, zmask, zshift);
  }
}

// Round 3
// 329.950 us; speedup vs baseline: 1.0912x; 1.0912x over previous
//
#include <hip/hip_runtime.h>
#include <hip/hip_bf16.h>
#include <stdint.h>
#include <math.h>

#define DEVI __device__ __forceinline__

typedef __attribute__((ext_vector_type(8))) __bf16    bf16x8;
typedef __attribute__((ext_vector_type(8))) _Float16  f16x8;
typedef __attribute__((ext_vector_type(4))) float     f32x4;

constexpr int BM = 128, BN = 128, BK = 64;

DEVI unsigned int pack2(float a, float b) {
  unsigned short ha = __builtin_bit_cast(unsigned short, __float2bfloat16(a));
  unsigned short hb = __builtin_bit_cast(unsigned short, __float2bfloat16(b));
  return (unsigned int)ha | ((unsigned int)hb << 16);
}

// ---------------------------------------------------------------------------
// Merged fp32 -> bf16 conversion for x, Wq, Wk, Wv in ONE launch.
// ---------------------------------------------------------------------------
__global__ __launch_bounds__(256) void k_cvt_all(const float* __restrict__ x,
                                                 const float* __restrict__ Wq,
                                                 const float* __restrict__ Wk,
                                                 const float* __restrict__ Wv,
                                                 __hip_bfloat16* __restrict__ xb,
                                                 __hip_bfloat16* __restrict__ Wqb,
                                                 __hip_bfloat16* __restrict__ Wkb,
                                                 __hip_bfloat16* __restrict__ Wvb) {
  int i = blockIdx.x * 256 + threadIdx.x;
  const float* src;
  __hip_bfloat16* dst;
  int k;
  if (i < 4194304) {
    src = x; dst = xb; k = i;
  } else {
    int j = i - 4194304;
    int w = j >> 18;
    k = j & 262143;
    src = (w == 0) ? Wq : (w == 1) ? Wk : Wv;
    dst = (w == 0) ? Wqb : (w == 1) ? Wkb : Wvb;
  }
  float4 f = ((const float4*)src)[k];
  uint2 u;
  u.x = pack2(f.x, f.y);
  u.y = pack2(f.z, f.w);
  ((uint2*)dst)[k] = u;
}

// ---------------------------------------------------------------------------
// Staging: global -> LDS via global_load_lds (16B/lane), wave-uniform LDS
// base. XOR swizzle on the GLOBAL column so ds_read_b128 fragment reads
// spread across banks. LDS (row,k) at row*64 + ((k/8)^(row&7))*8 + k%8.
// NR = number of 64-col rows staged (multiple of 32 with 256 threads).
// ---------------------------------------------------------------------------
template<int NR>
DEVI void stage_rows(const __hip_bfloat16* gbase, int ld, unsigned short* lds, int tid) {
#pragma unroll
  for (int j = 0; j < NR / 32; ++j) {
    int g   = j * 256 + tid;
    int row = g >> 3;
    int cp  = g & 7;
    int c   = cp ^ (row & 7);
    const __hip_bfloat16* src = gbase + (size_t)row * ld + c * 8;
    unsigned short* dst = lds + (size_t)(j * 256 + (tid & ~63)) * 8;  // wave-uniform
    __builtin_amdgcn_global_load_lds((__attribute__((address_space(1))) void*)(src),
                                     (__attribute__((address_space(3))) void*)(dst),
                                     16, 0, 0);
  }
}

DEVI void stage_tile(const __hip_bfloat16* gbase, int ld, unsigned short* lds, int tid) {
  stage_rows<128>(gbase, ld, lds, tid);
}

DEVI bf16x8 read_frag(const unsigned short* lds, int row, int kcol) {
  int c  = kcol >> 3;
  int cp = c ^ (row & 7);
  return *(const bf16x8*)(lds + row * 64 + cp * 8);
}

// ---------------------------------------------------------------------------
// 128x128x(64*ktiles) bf16 MFMA core, gemm_bt (proven; used by proj/scores).
// ---------------------------------------------------------------------------
DEVI void gemm_core(unsigned short* sA, unsigned short* sB,
                    const __hip_bfloat16* A0, int lda,
                    const __hip_bfloat16* B0, int ldb,
                    int ktiles, f32x4 (&acc)[4][4]) {
  const int tid  = threadIdx.x;
  const int lane = tid & 63;
  const int wid  = tid >> 6;
  const int quad = lane >> 4;
  const int lr   = lane & 15;
  const int wm   = (wid >> 1) * 64;
  const int wn   = (wid & 1) * 64;
  const f32x4 Z = {0.f, 0.f, 0.f, 0.f};
#pragma unroll
  for (int i = 0; i < 4; ++i)
#pragma unroll
    for (int j = 0; j < 4; ++j) acc[i][j] = Z;

  for (int kt = 0; kt < ktiles; ++kt) {
    stage_tile(A0 + kt * BK, lda, sA, tid);
    stage_tile(B0 + kt * BK, ldb, sB, tid);
    __syncthreads();
#pragma unroll
    for (int ks = 0; ks < BK; ks += 32) {
      bf16x8 af[4], bfr[4];
#pragma unroll
      for (int t = 0; t < 4; ++t) af[t]  = read_frag(sA, wm + t * 16 + lr, ks + quad * 8);
#pragma unroll
      for (int t = 0; t < 4; ++t) bfr[t] = read_frag(sB, wn + t * 16 + lr, ks + quad * 8);
#pragma unroll
      for (int i = 0; i < 4; ++i)
#pragma unroll
        for (int j = 0; j < 4; ++j)
          acc[i][j] = __builtin_amdgcn_mfma_f32_16x16x32_bf16(af[i], bfr[j], acc[i][j], 0, 0, 0);
    }
    __syncthreads();
  }
}

// ---------------------------------------------------------------------------
// Merged QKV projection (one launch, grid 3072). Inner XCD swizzle keeps a
// 4MB per-XCD X working set. V stored per-batch transposed Vt[b][e][s].
// (Round-0 proven version: 104.8 us, MfmaUtil 45%.)
// ---------------------------------------------------------------------------
__global__ __launch_bounds__(256, 4) void k_proj_qkv(const __hip_bfloat16* __restrict__ X,
                                                     const __hip_bfloat16* __restrict__ Wq,
                                                     const __hip_bfloat16* __restrict__ Wk,
                                                     const __hip_bfloat16* __restrict__ Wv,
                                                     const float* __restrict__ bq,
                                                     const float* __restrict__ bk,
                                                     const float* __restrict__ bv,
                                                     __hip_bfloat16* __restrict__ Q,
                                                     __hip_bfloat16* __restrict__ Kp,
                                                     __hip_bfloat16* __restrict__ Vt) {
  __shared__ unsigned short sA[BM * BK];
  __shared__ unsigned short sB[BN * BK];
  const int id = blockIdx.x;
  const int w  = id >> 10;                    // 0=Q 1=K 2=V
  const int i2 = id & 1023;
  const int mt = ((i2 & 7) << 4) | ((i2 >> 3) & 15);
  const int nt = i2 >> 7;
  const int m0 = mt * BM;
  const int n0 = nt * BN;

  const __hip_bfloat16* W = (w == 0) ? Wq : (w == 1) ? Wk : Wv;
  const float* bias       = (w == 0) ? bq : (w == 1) ? bk : bv;

  f32x4 acc[4][4];
  gemm_core(sA, sB, X + (size_t)m0 * 1024, 1024, W + (size_t)n0 * 1024, 1024, 16, acc);

  const int tid = threadIdx.x, lane = tid & 63, wid = tid >> 6;
  const int quad = lane >> 4, lr = lane & 15;
  const int wm = (wid >> 1) * 64, wn = (wid & 1) * 64;
  float bvv[4];
#pragma unroll
  for (int j = 0; j < 4; ++j) bvv[j] = bias[n0 + wn + j * 16 + lr];

  if (w != 2) {
    __hip_bfloat16* C = (w == 0) ? Q : Kp;
#pragma unroll
    for (int i = 0; i < 4; ++i)
#pragma unroll
      for (int j = 0; j < 4; ++j) {
        int n = n0 + wn + j * 16 + lr;
#pragma unroll
        for (int r = 0; r < 4; ++r) {
          int m = m0 + wm + i * 16 + quad * 4 + r;
          C[(size_t)m * 1024 + n] = __float2bfloat16(acc[i][j][r] + bvv[j]);
        }
      }
  } else {
    const int b = m0 >> 11;
    __hip_bfloat16* Cb = Vt + ((size_t)b << 21);
    const int sb = (m0 & 2047) + wm;
#pragma unroll
    for (int i = 0; i < 4; ++i)
#pragma unroll
      for (int j = 0; j < 4; ++j) {
        int n  = n0 + wn + j * 16 + lr;
        int s0 = sb + i * 16 + quad * 4;
        uint2 u;
        u.x = pack2(acc[i][j][0] + bvv[j], acc[i][j][1] + bvv[j]);
        u.y = pack2(acc[i][j][2] + bvv[j], acc[i][j][3] + bvv[j]);
        *(uint2*)(Cb + (size_t)n * 2048 + s0) = u;
      }
  }
}

// ---------------------------------------------------------------------------
// Scores: S[z,q,k] = (Q.K)/32, fp16, lower-triangular tiles only.
// Grid G*136; z = id & zmask (batch <-> XCD), triangular tile decode.
// ---------------------------------------------------------------------------
__global__ __launch_bounds__(256, 4) void k_scores(const __hip_bfloat16* __restrict__ Q,
                                                   const __hip_bfloat16* __restrict__ Kmat,
                                                   _Float16* __restrict__ S,
                                                   int b0, int zmask, int zshift) {
  __shared__ unsigned short sA[BM * BK];
  __shared__ unsigned short sB[BN * BK];
  const int id = blockIdx.x;
  const int z = id & zmask;
  const int b = b0 + z;
  const int i = id >> zshift;
  int qt = (int)((sqrtf(8.f * (float)i + 1.f) - 1.f) * 0.5f);
  while ((qt + 1) * (qt + 2) / 2 <= i) ++qt;
  while (qt * (qt + 1) / 2 > i) --qt;
  const int kt = i - qt * (qt + 1) / 2;

  const int m0 = qt * BM, n0 = kt * BN;
  f32x4 acc[4][4];
  const __hip_bfloat16* A0 = Q    + ((size_t)b << 21) + (size_t)m0 * 1024;
  const __hip_bfloat16* B0 = Kmat + ((size_t)b << 21) + (size_t)n0 * 1024;
  gemm_core(sA, sB, A0, 1024, B0, 1024, 16, acc);

  _Float16* Sb = S + ((size_t)z << 22);
  const int tid = threadIdx.x, lane = tid & 63, wid = tid >> 6;
  const int quad = lane >> 4, lr = lane & 15;
  const int wm = (wid >> 1) * 64, wn = (wid & 1) * 64;
#pragma unroll
  for (int i2 = 0; i2 < 4; ++i2)
#pragma unroll
    for (int j = 0; j < 4; ++j) {
      int n = n0 + wn + j * 16 + lr;
#pragma unroll
      for (int r = 0; r < 4; ++r) {
        int m = m0 + wm + i2 * 16 + quad * 4 + r;
        Sb[(size_t)m * 2048 + n] = (_Float16)(acc[i2][j][r] * 0.03125f);
      }
    }
}

// ---------------------------------------------------------------------------
// Row softmax over k<=q, in-place. ONE WAVE PER ROW (4 rows per 256-thr
// block): no LDS, no __syncthreads, pure shfl reduction across 64 lanes.
// Each lane handles 4 x f16x8 segments (32 cols). k>q written as 0.
// Grid G*512.
// ---------------------------------------------------------------------------
__global__ __launch_bounds__(256) void k_softmax(_Float16* __restrict__ S) {
  const int wid  = threadIdx.x >> 6;
  const int lane = threadIdx.x & 63;
  const int row  = blockIdx.x * 4 + wid;
  const int q    = row & 2047;
  _Float16* srow = S + ((size_t)row << 11);

  float v[4][8];
  float mx = -1e30f;
#pragma unroll
  for (int it = 0; it < 4; ++it) {
    int k0 = it * 512 + lane * 8;
    if (k0 <= q) {
      f16x8 h = ((const f16x8*)srow)[it * 64 + lane];
#pragma unroll
      for (int i = 0; i < 8; ++i) {
        float f = (float)h[i];
        v[it][i] = (k0 + i <= q) ? f : -1e30f;
        mx = fmaxf(mx, v[it][i]);
      }
    } else {
#pragma unroll
      for (int i = 0; i < 8; ++i) v[it][i] = -1e30f;
    }
  }
#pragma unroll
  for (int off = 32; off > 0; off >>= 1) mx = fmaxf(mx, __shfl_xor(mx, off));

  float e[4][8], s = 0.f;
#pragma unroll
  for (int it = 0; it < 4; ++it)
#pragma unroll
    for (int i = 0; i < 8; ++i) { e[it][i] = __expf(v[it][i] - mx); s += e[it][i]; }
#pragma unroll
  for (int off = 32; off > 0; off >>= 1) s += __shfl_xor(s, off);
  const float inv = 1.0f / s;

#pragma unroll
  for (int it = 0; it < 4; ++it) {
    bf16x8 o;
#pragma unroll
    for (int i = 0; i < 8; ++i) o[i] = (__bf16)(e[it][i] * inv);
    ((bf16x8*)srow)[it * 64 + lane] = o;
  }
}

// ---------------------------------------------------------------------------
// PV: out[b,q,e] = sum_s P[q,s]*Vt[e,s], fp32 out. BM=128, BN=64 so the
// grid is G*128 (pairs p x 16 n-tiles): 2 blocks/CU at G=4, 4/CU at G=8
// (old BN=128 grid was 1 block/CU = 1 wave/SIMD at G=4 -> latency-bound).
// Load-balanced pairing: (qt=15-p, nt) then (qt=p, nt) -> uniform 34 ktiles.
// ---------------------------------------------------------------------------
DEVI void pv_core(unsigned short* sA, unsigned short* sB,
                  const __hip_bfloat16* A0, const __hip_bfloat16* B0,
                  int ktiles, f32x4 (&acc)[4][2]) {
  const int tid  = threadIdx.x;
  const int lane = tid & 63;
  const int wid  = tid >> 6;
  const int quad = lane >> 4;
  const int lr   = lane & 15;
  const int wm   = (wid >> 1) * 64;
  const int wn   = (wid & 1) * 32;
  const f32x4 Z = {0.f, 0.f, 0.f, 0.f};
#pragma unroll
  for (int i = 0; i < 4; ++i)
#pragma unroll
    for (int j = 0; j < 2; ++j) acc[i][j] = Z;

  for (int kt = 0; kt < ktiles; ++kt) {
    stage_rows<128>(A0 + kt * BK, 2048, sA, tid);
    stage_rows<64> (B0 + kt * BK, 2048, sB, tid);
    __syncthreads();
#pragma unroll
    for (int ks = 0; ks < BK; ks += 32) {
      bf16x8 af[4], bfr[2];
#pragma unroll
      for (int t = 0; t < 4; ++t) af[t]  = read_frag(sA, wm + t * 16 + lr, ks + quad * 8);
#pragma unroll
      for (int t = 0; t < 2; ++t) bfr[t] = read_frag(sB, wn + t * 16 + lr, ks + quad * 8);
#pragma unroll
      for (int i = 0; i < 4; ++i)
#pragma unroll
        for (int j = 0; j < 2; ++j)
          acc[i][j] = __builtin_amdgcn_mfma_f32_16x16x32_bf16(af[i], bfr[j], acc[i][j], 0, 0, 0);
    }
    __syncthreads();
  }
}

DEVI void pv_one(unsigned short* sA, unsigned short* sB,
                 const __hip_bfloat16* P, const __hip_bfloat16* VtB,
                 float* Cb, int qt, int nt) {
  const int m0 = qt * BM, n0 = nt * 64;
  const int ktiles = 2 * qt + 2;   // covers s in [0, (qt+1)*128)
  f32x4 acc[4][2];
  pv_core(sA, sB, P + (size_t)m0 * 2048, VtB + (size_t)n0 * 2048, ktiles, acc);

  const int tid = threadIdx.x, lane = tid & 63, wid = tid >> 6;
  const int quad = lane >> 4, lr = lane & 15;
  const int wm = (wid >> 1) * 64, wn = (wid & 1) * 32;
#pragma unroll
  for (int i = 0; i < 4; ++i)
#pragma unroll
    for (int j = 0; j < 2; ++j) {
      int n = n0 + wn + j * 16 + lr;
#pragma unroll
      for (int r = 0; r < 4; ++r) {
        int m = m0 + wm + i * 16 + quad * 4 + r;
        Cb[(size_t)m * 1024 + n] = acc[i][j][r];
      }
    }
}

__global__ __launch_bounds__(256, 4) void k_pv(const _Float16* __restrict__ Sbase,
                                               const __hip_bfloat16* __restrict__ Vt,
                                               float* __restrict__ out,
                                               int b0, int zmask, int zshift) {
  __shared__ unsigned short sA[BM * BK];
  __shared__ unsigned short sB[64 * BK];
  const int id = blockIdx.x;
  const int z = id & zmask;
  const int b = b0 + z;
  const int r2 = id >> zshift;     // 0..127
  const int nt = r2 & 15;
  const int p  = (r2 >> 4) & 7;
  const __hip_bfloat16* P   = (const __hip_bfloat16*)(Sbase + ((size_t)z << 22));
  const __hip_bfloat16* VtB = Vt + ((size_t)b << 21);
  float* Cb = out + ((size_t)b << 21);
  pv_one(sA, sB, P, VtB, Cb, 15 - p, nt);   // long tile first
  pv_one(sA, sB, P, VtB, Cb, p, nt);        // short tile second
}

extern "C" void kernel_launch(void* const* d_in, const int* in_sizes, int n_in,
                              void* d_out, int out_size, void* d_ws, size_t ws_size,
                              hipStream_t stream) {
  const float* x  = (const float*)d_in[0];
  const float* Wq = (const float*)d_in[1];
  const float* bq = (const float*)d_in[2];
  const float* Wk = (const float*)d_in[3];
  const float* bk = (const float*)d_in[4];
  const float* Wv = (const float*)d_in[5];
  const float* bv = (const float*)d_in[6];
  float* out = (float*)d_out;

  char* ws = (char*)d_ws;
  const size_t MB32 = (size_t)33554432;
  const size_t MB64 = (size_t)67108864;

  __hip_bfloat16 *xb, *Wqb, *Wkb, *Wvb, *Q, *Kp, *Vt;
  _Float16* S;
  int G;
  if (ws_size >= (size_t)174063616) {
    // Big layout (166 MiB): [S 64MB (xb overlays first 32MB)] [W 6MB] [Q][K][Vt]
    S   = (_Float16*)(ws);
    xb  = (__hip_bfloat16*)(ws);                   // dead before S is written
    Wqb = (__hip_bfloat16*)(ws + MB64);
    Wkb = (__hip_bfloat16*)(ws + MB64 + 2097152);
    Wvb = (__hip_bfloat16*)(ws + MB64 + 4194304);
    Q   = (__hip_bfloat16*)(ws + MB64 + 6291456);
    Kp  = (__hip_bfloat16*)(ws + MB64 + 6291456 + MB32);
    Vt  = (__hip_bfloat16*)(ws + MB64 + 6291456 + 2 * MB32);
    G = 8;
  } else {
    // Small layout (134 MiB, proven): [xb 32MB == S 32MB] [W 6MB] [Q][K][Vt]
    S   = (_Float16*)(ws);
    xb  = (__hip_bfloat16*)(ws);
    Wqb = (__hip_bfloat16*)(ws + MB32);
    Wkb = (__hip_bfloat16*)(ws + MB32 + 2097152);
    Wvb = (__hip_bfloat16*)(ws + MB32 + 4194304);
    Q   = (__hip_bfloat16*)(ws + MB32 + 6291456);
    Kp  = (__hip_bfloat16*)(ws + 2 * MB32 + 6291456);
    Vt  = (__hip_bfloat16*)(ws + 3 * MB32 + 6291456);
    G = 4;
  }
  const int zmask  = G - 1;
  const int zshift = (G == 8) ? 3 : 2;

  dim3 blk(256);
  k_cvt_all<<<dim3(19456), blk, 0, stream>>>(x, Wq, Wk, Wv, xb, Wqb, Wkb, Wvb);
  k_proj_qkv<<<dim3(3072), blk, 0, stream>>>(xb, Wqb, Wkb, Wvb, bq, bk, bv, Q, Kp, Vt);

  for (int b0 = 0; b0 < 8; b0 += G) {
    k_scores <<<dim3(G * 136), blk, 0, stream>>>(Q, Kp, S, b0, zmask, zshift);
    k_softmax<<<dim3(G * 512), blk, 0, stream>>>(S);
    k_pv     <<<dim3(G * 128), blk, 0, stream>>>(S, Vt, out, b0, zmask, zshift);
  }
}